// Round 1
// baseline (739.702 us; speedup 1.0000x reference)
//
#include <hip/hip_runtime.h>

#define D 128
#define CAP 64    // padded CSR slots per node; P(indeg>=64 | Poisson(16)) ~ 1e-21, guarded
#define PADR 136  // shorts per LDS agg row (272 B) — breaks power-of-2 bank stride

// binning: bucket = dst>>7 (128 nodes/bucket), stride-4096 slots (~45 sigma above 2048 mean)
#define BSHIFT 7
#define BSTRIDE 4096

typedef short short8 __attribute__((ext_vector_type(8)));
typedef float floatx4 __attribute__((ext_vector_type(4)));

static __device__ __forceinline__ unsigned short f2bf(float f) {
    unsigned int u = __float_as_uint(f);
    u += 0x7fffu + ((u >> 16) & 1u);   // RNE
    return (unsigned short)(u >> 16);
}
static __device__ __forceinline__ unsigned int pack2bf(float a, float b) {
    return (unsigned int)f2bf(a) | ((unsigned int)f2bf(b) << 16);
}
// read 16-bit counter v from packed array
static __device__ __forceinline__ int rd16(const unsigned int* __restrict__ pc, int v) {
    return (int)((pc[v >> 1] >> ((v & 1) * 16)) & 0xffffu);
}

// ---------------- pass A: src histogram + bin edges by dst ----------------
// bdata[b*BSTRIDE + p] = (d&127)<<17 | s   (s < 2^17, d_local < 2^7)
// Appends to a bucket are sequential -> L2 write-combining (vs 23x line
// amplification of direct random CSR scatter).
__global__ void k_bin(const int2* __restrict__ se2, const int2* __restrict__ de2,
                      unsigned int* __restrict__ pcnt_out,
                      unsigned int* __restrict__ bdata, unsigned int* __restrict__ bcur,
                      int npairs) {
    int i = blockIdx.x * blockDim.x + threadIdx.x;
    if (i >= npairs) return;
    int2 ss = se2[i];
    int2 dd = de2[i];
#pragma unroll
    for (int j = 0; j < 2; j++) {
        int s = (j == 0) ? ss.x : ss.y;
        int d = (j == 0) ? dd.x : dd.y;
        atomicAdd(&pcnt_out[s >> 1], 1u << ((s & 1) * 16));   // non-returning
        int b = d >> BSHIFT;
        unsigned int p = atomicAdd(&bcur[b], 1u);
        if (p < BSTRIDE)
            bdata[((size_t)b << 12) + p] = ((unsigned int)(d & 127) << 17) | (unsigned int)s;
    }
}

// ---------------- pass B: per-bucket CSR build (LDS counters, local scatter) ----------------
__global__ __launch_bounds__(256) void k_csr(
    const unsigned int* __restrict__ bdata, const unsigned int* __restrict__ bcur,
    unsigned int* __restrict__ pcnt_in, int* __restrict__ esrc, int n) {
    __shared__ unsigned int lcnt[128];
    int b = blockIdx.x;
    int base = b << BSHIFT;
    if (threadIdx.x < 128) lcnt[threadIdx.x] = 0;
    __syncthreads();
    int cnt = (int)bcur[b];
    if (cnt > BSTRIDE) cnt = BSTRIDE;
    const unsigned int* bp = bdata + ((size_t)b << 12);
    for (int i = threadIdx.x; i < cnt; i += 256) {
        unsigned int e = bp[i];
        int s = (int)(e & 0x1FFFFu);
        int dl = (int)(e >> 17);
        unsigned int p = atomicAdd(&lcnt[dl], 1u);
        if (p < CAP) esrc[((size_t)(base + dl) << 6) + p] = s;
    }
    __syncthreads();
    // write packed in-degree counters wholesale (no global memset needed)
    if (threadIdx.x < 64) {
        int node0 = base + threadIdx.x * 2;
        if (node0 < n) {
            unsigned int c0 = lcnt[threadIdx.x * 2];
            unsigned int c1 = lcnt[threadIdx.x * 2 + 1];
            pcnt_in[(base >> 1) + threadIdx.x] = (c0 & 0xffffu) | (c1 << 16);
        }
    }
}

// ---------------- prep: prescale x (fused inv) + W transpose/bf16 ----------------
__global__ void k_prep(const float* __restrict__ x, const unsigned int* __restrict__ pcnt_out,
                       float* __restrict__ inv, uint2* __restrict__ xb2, int total4,
                       const float* __restrict__ W1, const float* __restrict__ W2,
                       unsigned short* __restrict__ WT1, unsigned short* __restrict__ WT2) {
    int b = blockIdx.x;
    int nb4 = (total4 + 255) >> 8;
    if (b >= nb4) {  // W-prep tail blocks: 128 blocks, WT[n][k] = bf16(W[k][n])
        int bb = b - nb4;
        const float* W = (bb < 64) ? W1 : W2;
        unsigned short* WT = (bb < 64) ? WT1 : WT2;
        int idx = (bb & 63) * 256 + threadIdx.x;
        int k = idx >> 7, nn = idx & 127;
        WT[nn * 128 + k] = f2bf(W[idx]);
        return;
    }
    int i = b * 256 + threadIdx.x;
    if (i >= total4) return;
    int row = i >> 5;                 // 32 float4 per row
    int d = rd16(pcnt_out, row);
    float s = 1.0f / (float)(d > 1 ? d : 1);
    if ((i & 31) == 0) inv[row] = s;
    float4 v = ((const float4*)x)[i];
    uint2 o;
    o.x = pack2bf(v.x * s, v.y * s);
    o.y = pack2bf(v.z * s, v.w * s);
    xb2[i] = o;
}

// ---------------- fused layer: quarter-wave gather into LDS + MFMA 16x128 transform ----------------
template<bool OUTBF>
__global__ __launch_bounds__(256) void k_fused(
    const uint4* __restrict__ hb4, const unsigned int* __restrict__ pcnt_in,
    const int* __restrict__ esrc, const unsigned short* __restrict__ WT,
    const float* __restrict__ bias, const float* __restrict__ pa,
    const float* __restrict__ inv, void* __restrict__ outp, int n)
{
    __shared__ unsigned short sAgg[16 * PADR];   // 4.25 KB
    int wv = threadIdx.x >> 6;
    int lane = threadIdx.x & 63;
    int q = lane >> 4;    // edge sub-slot / k-chunk
    int f = lane & 15;    // 16-byte feature chunk
    int nb = blockIdx.x * 16;

    // ---- gather phase: 4 nodes per wave ----
    for (int i = 0; i < 4; i++) {
        int node = nb + wv * 4 + i;
        if (node >= n) break;
        int cnt = rd16(pcnt_in, node);
        if (cnt > CAP) cnt = CAP;
        const int* ep = esrc + (node << 6);

        float acc[8];
#pragma unroll
        for (int j = 0; j < 8; j++) acc[j] = 0.f;

        for (int base = 0; base < cnt; base += 8) {
            int e0 = base + q, e1 = base + 4 + q;
            if (e0 < cnt) {
                uint4 v = hb4[(size_t)ep[e0] * 16 + f];
                acc[0] += __uint_as_float(v.x << 16);  acc[1] += __uint_as_float(v.x & 0xffff0000u);
                acc[2] += __uint_as_float(v.y << 16);  acc[3] += __uint_as_float(v.y & 0xffff0000u);
                acc[4] += __uint_as_float(v.z << 16);  acc[5] += __uint_as_float(v.z & 0xffff0000u);
                acc[6] += __uint_as_float(v.w << 16);  acc[7] += __uint_as_float(v.w & 0xffff0000u);
            }
            if (e1 < cnt) {
                uint4 v = hb4[(size_t)ep[e1] * 16 + f];
                acc[0] += __uint_as_float(v.x << 16);  acc[1] += __uint_as_float(v.x & 0xffff0000u);
                acc[2] += __uint_as_float(v.y << 16);  acc[3] += __uint_as_float(v.y & 0xffff0000u);
                acc[4] += __uint_as_float(v.z << 16);  acc[5] += __uint_as_float(v.z & 0xffff0000u);
                acc[6] += __uint_as_float(v.w << 16);  acc[7] += __uint_as_float(v.w & 0xffff0000u);
            }
        }
#pragma unroll
        for (int j = 0; j < 8; j++) {
            acc[j] += __shfl_xor(acc[j], 16, 64);
            acc[j] += __shfl_xor(acc[j], 32, 64);
        }
        if (q == 0) {
            uint4 o;
            o.x = pack2bf(acc[0], acc[1]);
            o.y = pack2bf(acc[2], acc[3]);
            o.z = pack2bf(acc[4], acc[5]);
            o.w = pack2bf(acc[6], acc[7]);
            *(uint4*)&sAgg[(wv * 4 + i) * PADR + f * 8] = o;
        }
    }
    __syncthreads();

    // ---- transform phase: wave w does col-tiles {2w, 2w+1} ----
    int m = lane & 15;
    short8 a0 = *(const short8*)&sAgg[m * PADR +   0 + q * 8];
    short8 a1 = *(const short8*)&sAgg[m * PADR +  32 + q * 8];
    short8 a2 = *(const short8*)&sAgg[m * PADR +  64 + q * 8];
    short8 a3 = *(const short8*)&sAgg[m * PADR +  96 + q * 8];

    float alpha = pa[0];
    float* outf = (float*)outp;
    unsigned short* outb = (unsigned short*)outp;

    float invr[4];
    if (OUTBF) {
#pragma unroll
        for (int r = 0; r < 4; r++) {
            int row = nb + q * 4 + r;
            invr[r] = (row < n) ? inv[row] : 1.f;
        }
    }

#pragma unroll
    for (int tt = 0; tt < 2; tt++) {
        int t = wv * 2 + tt;
        int col = t * 16 + m;
        const short8* Bp = (const short8*)(WT + (size_t)col * 128 + q * 8);
        floatx4 acc = {0.f, 0.f, 0.f, 0.f};
        acc = __builtin_amdgcn_mfma_f32_16x16x32_bf16(a0, Bp[0],  acc, 0, 0, 0);
        acc = __builtin_amdgcn_mfma_f32_16x16x32_bf16(a1, Bp[4],  acc, 0, 0, 0);
        acc = __builtin_amdgcn_mfma_f32_16x16x32_bf16(a2, Bp[8],  acc, 0, 0, 0);
        acc = __builtin_amdgcn_mfma_f32_16x16x32_bf16(a3, Bp[12], acc, 0, 0, 0);
        float bb = bias[col];
#pragma unroll
        for (int r = 0; r < 4; r++) {
            int row = nb + q * 4 + r;   // C/D: col=lane&15, row=(lane>>4)*4+reg
            if (row < n) {
                float z = acc[r] + bb;
                z = (z >= 0.f) ? z : alpha * z;
                if (OUTBF)
                    outb[(size_t)row * 128 + col] = f2bf(z * invr[r]);
                else
                    outf[(size_t)row * 128 + col] = z;
            }
        }
    }
}

// ---------------- standalone gather (fallback path, layer 2) ----------------
__global__ __launch_bounds__(256) void k_gather(
    const uint4* __restrict__ hb4, const unsigned int* __restrict__ pcnt_in,
    const int* __restrict__ esrc, uint4* __restrict__ aggb4, int n)
{
    int lane = threadIdx.x & 63;
    int node = blockIdx.x * 4 + (threadIdx.x >> 6);
    if (node >= n) return;
    int q = lane >> 4, f = lane & 15;
    int cnt = rd16(pcnt_in, node);
    if (cnt > CAP) cnt = CAP;
    const int* ep = esrc + (node << 6);

    float acc[8];
#pragma unroll
    for (int j = 0; j < 8; j++) acc[j] = 0.f;

    for (int base = 0; base < cnt; base += 8) {
        int e0 = base + q, e1 = base + 4 + q;
        if (e0 < cnt) {
            uint4 v = hb4[(size_t)ep[e0] * 16 + f];
            acc[0] += __uint_as_float(v.x << 16);  acc[1] += __uint_as_float(v.x & 0xffff0000u);
            acc[2] += __uint_as_float(v.y << 16);  acc[3] += __uint_as_float(v.y & 0xffff0000u);
            acc[4] += __uint_as_float(v.z << 16);  acc[5] += __uint_as_float(v.z & 0xffff0000u);
            acc[6] += __uint_as_float(v.w << 16);  acc[7] += __uint_as_float(v.w & 0xffff0000u);
        }
        if (e1 < cnt) {
            uint4 v = hb4[(size_t)ep[e1] * 16 + f];
            acc[0] += __uint_as_float(v.x << 16);  acc[1] += __uint_as_float(v.x & 0xffff0000u);
            acc[2] += __uint_as_float(v.y << 16);  acc[3] += __uint_as_float(v.y & 0xffff0000u);
            acc[4] += __uint_as_float(v.z << 16);  acc[5] += __uint_as_float(v.z & 0xffff0000u);
            acc[6] += __uint_as_float(v.w << 16);  acc[7] += __uint_as_float(v.w & 0xffff0000u);
        }
    }
#pragma unroll
    for (int j = 0; j < 8; j++) {
        acc[j] += __shfl_xor(acc[j], 16, 64);
        acc[j] += __shfl_xor(acc[j], 32, 64);
    }
    if (q == 0) {
        uint4 o;
        o.x = pack2bf(acc[0], acc[1]);
        o.y = pack2bf(acc[2], acc[3]);
        o.z = pack2bf(acc[4], acc[5]);
        o.w = pack2bf(acc[6], acc[7]);
        aggb4[(size_t)node * 16 + f] = o;
    }
}

// ---------------- standalone MFMA GEMM (fallback path, layer 2) ----------------
__global__ __launch_bounds__(256) void k_gemm(
    const unsigned short* __restrict__ A, const unsigned short* __restrict__ WT,
    const float* __restrict__ bias, const float* __restrict__ pa,
    float* __restrict__ outf, int n)
{
    int lane = threadIdx.x & 63;
    int wv = threadIdx.x >> 6;
    int m = lane & 15, q = lane >> 4;
    int mbase = blockIdx.x * 64 + wv * 16;
    int arow = mbase + m;
    if (arow > n - 1) arow = n - 1;

    const short8* Ap = (const short8*)(A + (size_t)arow * 128 + q * 8);
    short8 a0 = Ap[0], a1 = Ap[4], a2 = Ap[8], a3 = Ap[12];

    float alpha = pa[0];
#pragma unroll
    for (int t = 0; t < 8; t++) {
        int col = t * 16 + m;
        const short8* Bp = (const short8*)(WT + (size_t)col * 128 + q * 8);
        floatx4 acc = {0.f, 0.f, 0.f, 0.f};
        acc = __builtin_amdgcn_mfma_f32_16x16x32_bf16(a0, Bp[0],  acc, 0, 0, 0);
        acc = __builtin_amdgcn_mfma_f32_16x16x32_bf16(a1, Bp[4],  acc, 0, 0, 0);
        acc = __builtin_amdgcn_mfma_f32_16x16x32_bf16(a2, Bp[8],  acc, 0, 0, 0);
        acc = __builtin_amdgcn_mfma_f32_16x16x32_bf16(a3, Bp[12], acc, 0, 0, 0);
        float bb = bias[col];
#pragma unroll
        for (int r = 0; r < 4; r++) {
            int row = mbase + q * 4 + r;
            if (row < n) {
                float z = acc[r] + bb;
                z = (z >= 0.f) ? z : alpha * z;
                outf[(size_t)row * 128 + col] = z;
            }
        }
    }
}

extern "C" void kernel_launch(void* const* d_in, const int* in_sizes, int n_in,
                              void* d_out, int out_size, void* d_ws, size_t ws_size,
                              hipStream_t stream) {
    const float* x   = (const float*)d_in[0];
    const int* src   = (const int*)d_in[1];
    const int* dst   = (const int*)d_in[2];
    const float* W1  = (const float*)d_in[3];
    const float* b1  = (const float*)d_in[4];
    const float* W2  = (const float*)d_in[5];
    const float* b2  = (const float*)d_in[6];
    const float* pa  = (const float*)d_in[7];
    float* out = (float*)d_out;

    const int N = in_sizes[0] / D;   // 100000
    const int E = in_sizes[1];       // 1600000

    // ---- workspace layout ----
    char* ws = (char*)d_ws;
    size_t off = 0;
    unsigned short* buf0 = (unsigned short*)(ws + off); off += (size_t)N * D * 2;  // xb; reused after layer 1
    unsigned short* buf1 = (unsigned short*)(ws + off); off += (size_t)N * D * 2;  // h1b
    unsigned int* pcnt_out = (unsigned int*)(ws + off); off += (size_t)((N + 1) / 2) * 4;
    unsigned int* pcnt_in  = (unsigned int*)(ws + off); off += (size_t)((N + 1) / 2) * 4;
    float* inv   = (float*)(ws + off); off += (size_t)N * sizeof(float);
    unsigned short* WT1 = (unsigned short*)(ws + off); off += 128 * 128 * 2;
    unsigned short* WT2 = (unsigned short*)(ws + off); off += 128 * 128 * 2;
    size_t off_esrc = off;
    size_t need_big = off_esrc + (size_t)N * CAP * sizeof(int);   // esrc in ws (~78 MB total)
    bool big = (ws_size >= need_big);

    // big path: esrc in ws -> both layers fully fused.
    // small path: esrc lives in d_out (dead before final k_gemm rewrites d_out); layer 2 split.
    int* esrc = big ? (int*)(ws + off_esrc) : (int*)d_out;

    // bucket structures alias onto buf1 (dead until k_fused layer 1 writes it):
    // bdata = NBUCK * BSTRIDE * 4B (~12.8 MB) + bcur (NBUCK * 4B) < 25.6 MB of buf1
    const int NBUCK = (N + (1 << BSHIFT) - 1) >> BSHIFT;   // 782
    unsigned int* bdata = (unsigned int*)buf1;
    unsigned int* bcur  = (unsigned int*)((char*)buf1 + (size_t)NBUCK * BSTRIDE * 4);

    // zero out-degree counters (200 KB) + bucket cursors (~3 KB); pcnt_in written wholesale by k_csr
    hipMemsetAsync(pcnt_out, 0, (size_t)((N + 1) / 2) * 4, stream);
    hipMemsetAsync(bcur, 0, (size_t)NBUCK * 4, stream);

    const int npairs = E / 2;
    k_bin<<<(npairs + 255) / 256, 256, 0, stream>>>((const int2*)src, (const int2*)dst,
                                                    pcnt_out, bdata, bcur, npairs);
    k_csr<<<NBUCK, 256, 0, stream>>>(bdata, bcur, pcnt_in, esrc, N);

    const int total4 = N * (D / 4);
    const int NBP = (total4 + 255) / 256 + 128;   // prescale blocks + 128 wprep blocks
    k_prep<<<NBP, 256, 0, stream>>>(x, pcnt_out, inv, (uint2*)buf0, total4, W1, W2, WT1, WT2);

    const int NBF = (N + 15) / 16;   // fused: 16 nodes per 256-thr block

    // layer 1: buf1 = bf16(prelu(segsum(xb)@W1 + b1) * inv[row])
    k_fused<true><<<NBF, 256, 0, stream>>>((const uint4*)buf0, pcnt_in, esrc, WT1, b1, pa, inv,
                                           (void*)buf1, N);

    if (big) {
        // layer 2 fused: out = fp32 prelu(segsum(buf1)@W2 + b2)
        k_fused<false><<<NBF, 256, 0, stream>>>((const uint4*)buf1, pcnt_in, esrc, WT2, b2, pa, inv,
                                                (void*)out, N);
    } else {
        // layer 2 split: gather (esrc in d_out, dead after) then gemm writes d_out
        const int NBG = (N + 3) / 4;
        const int NBM = (N + 63) / 64;
        k_gather<<<NBG, 256, 0, stream>>>((const uint4*)buf1, pcnt_in, esrc, (uint4*)buf0, N);
        k_gemm<<<NBM, 256, 0, stream>>>(buf0, WT2, b2, pa, out, N);
    }
}

// Round 2
// 396.191 us; speedup vs baseline: 1.8670x; 1.8670x over previous
//
#include <hip/hip_runtime.h>

#define D 128
#define CAP 64    // padded CSR slots per node; P(indeg>=64 | Poisson(16)) ~ 1e-21, guarded
#define PADR 136  // shorts per LDS agg row (272 B) — breaks power-of-2 bank stride

// counting sort: bucket = dst>>7 (128 nodes/bucket), 256 deterministic chunks
#define BSHIFT 7
#define NCH 256

typedef short short8 __attribute__((ext_vector_type(8)));
typedef float floatx4 __attribute__((ext_vector_type(4)));

static __device__ __forceinline__ unsigned short f2bf(float f) {
    unsigned int u = __float_as_uint(f);
    u += 0x7fffu + ((u >> 16) & 1u);   // RNE
    return (unsigned short)(u >> 16);
}
static __device__ __forceinline__ unsigned int pack2bf(float a, float b) {
    return (unsigned int)f2bf(a) | ((unsigned int)f2bf(b) << 16);
}
// read 16-bit counter v from packed array
static __device__ __forceinline__ int rd16(const unsigned int* __restrict__ pc, int v) {
    return (int)((pc[v >> 1] >> ((v & 1) * 16)) & 0xffffu);
}

// ---------------- pass 1: per-chunk bucket histogram (LDS only, no global atomics) ----------------
__global__ __launch_bounds__(512) void k_cnt(const int* __restrict__ dst,
                                             unsigned int* __restrict__ gcnt,
                                             int E, int cs, int nbuck) {
    __shared__ unsigned int h[1024];
    int b = blockIdx.x, t = threadIdx.x;
    for (int k = t; k < nbuck; k += 512) h[k] = 0;
    __syncthreads();
    int lo = b * cs, hi = lo + cs;
    if (hi > E) hi = E;
#pragma unroll 4
    for (int e = lo + t; e < hi; e += 512)
        atomicAdd(&h[(unsigned)dst[e] >> BSHIFT], 1u);
    __syncthreads();
    for (int k = t; k < nbuck; k += 512) gcnt[(size_t)b * nbuck + k] = h[k];
}

// ---------------- pass 2a: per-bucket exclusive scan over chunks (in-place) ----------------
__global__ __launch_bounds__(NCH) void k_pfx1(unsigned int* __restrict__ gcnt,
                                              unsigned int* __restrict__ btot, int nbuck) {
    __shared__ unsigned int sa[NCH], sb[NCH];
    int k = blockIdx.x, t = threadIdx.x;
    unsigned int v = gcnt[(size_t)t * nbuck + k];
    sa[t] = v;
    unsigned int* A = sa; unsigned int* B = sb;
    for (int off = 1; off < NCH; off <<= 1) {
        __syncthreads();
        B[t] = A[t] + ((t >= off) ? A[t - off] : 0u);
        unsigned int* tmp = A; A = B; B = tmp;
    }
    __syncthreads();
    unsigned int incl = A[t];
    gcnt[(size_t)t * nbuck + k] = incl - v;   // exclusive, in-place (column-private per block)
    if (t == NCH - 1) btot[k] = incl;
}

// ---------------- pass 2b: scan bucket totals -> bstart ----------------
__global__ __launch_bounds__(1024) void k_pfx2(const unsigned int* __restrict__ btot,
                                               unsigned int* __restrict__ bstart,
                                               int nbuck, int E) {
    __shared__ unsigned int sa[1024], sb[1024];
    int t = threadIdx.x;
    unsigned int v = (t < nbuck) ? btot[t] : 0u;
    sa[t] = v;
    unsigned int* A = sa; unsigned int* B = sb;
    for (int off = 1; off < 1024; off <<= 1) {
        __syncthreads();
        B[t] = A[t] + ((t >= off) ? A[t - off] : 0u);
        unsigned int* tmp = A; A = B; B = tmp;
    }
    __syncthreads();
    if (t < nbuck) bstart[t] = A[t] - v;
    if (t == 0) bstart[nbuck] = (unsigned int)E;
}

// ---------------- pass 3: deterministic scatter into dense bdata + src histogram ----------------
// Each (chunk,bucket) range is block-private and contiguous -> lines filled by one XCD.
__global__ __launch_bounds__(512) void k_scat(const int* __restrict__ src, const int* __restrict__ dst,
                                              const unsigned int* __restrict__ goff,
                                              const unsigned int* __restrict__ bstart,
                                              unsigned int* __restrict__ pcnt_out,
                                              unsigned int* __restrict__ bdata,
                                              int E, int cs, int nbuck) {
    __shared__ unsigned int cur[1024];
    int b = blockIdx.x, t = threadIdx.x;
    for (int k = t; k < nbuck; k += 512)
        cur[k] = bstart[k] + goff[(size_t)b * nbuck + k];
    __syncthreads();
    int lo = b * cs, hi = lo + cs;
    if (hi > E) hi = E;
#pragma unroll 2
    for (int e = lo + t; e < hi; e += 512) {
        int s = src[e];
        int d = dst[e];
        atomicAdd(&pcnt_out[s >> 1], 1u << ((s & 1) * 16));   // non-returning
        unsigned int p = atomicAdd(&cur[(unsigned)d >> BSHIFT], 1u);
        bdata[p] = ((unsigned int)(d & 127) << 17) | (unsigned int)s;
    }
}

// ---------------- pass 4: per-bucket CSR build (LDS counters, local scatter) ----------------
__global__ __launch_bounds__(256) void k_csr(
    const unsigned int* __restrict__ bdata, const unsigned int* __restrict__ bstart,
    unsigned int* __restrict__ pcnt_in, int* __restrict__ esrc, int n) {
    __shared__ unsigned int lcnt[128];
    int b = blockIdx.x;
    int base = b << BSHIFT;
    if (threadIdx.x < 128) lcnt[threadIdx.x] = 0;
    __syncthreads();
    int lo = (int)bstart[b], hi = (int)bstart[b + 1];
    for (int i = lo + threadIdx.x; i < hi; i += 256) {
        unsigned int e = bdata[i];
        int s = (int)(e & 0x1FFFFu);
        int dl = (int)(e >> 17);
        unsigned int p = atomicAdd(&lcnt[dl], 1u);
        if (p < CAP) esrc[((size_t)(base + dl) << 6) + p] = s;
    }
    __syncthreads();
    // write packed in-degree counters wholesale (no global memset needed)
    if (threadIdx.x < 64) {
        int node0 = base + threadIdx.x * 2;
        if (node0 < n) {
            unsigned int c0 = lcnt[threadIdx.x * 2];
            unsigned int c1 = lcnt[threadIdx.x * 2 + 1];
            pcnt_in[(base >> 1) + threadIdx.x] = (c0 & 0xffffu) | (c1 << 16);
        }
    }
}

// ---------------- prep: prescale x (fused inv) + W transpose/bf16 ----------------
__global__ void k_prep(const float* __restrict__ x, const unsigned int* __restrict__ pcnt_out,
                       float* __restrict__ inv, uint2* __restrict__ xb2, int total4,
                       const float* __restrict__ W1, const float* __restrict__ W2,
                       unsigned short* __restrict__ WT1, unsigned short* __restrict__ WT2) {
    int b = blockIdx.x;
    int nb4 = (total4 + 255) >> 8;
    if (b >= nb4) {  // W-prep tail blocks: 128 blocks, WT[n][k] = bf16(W[k][n])
        int bb = b - nb4;
        const float* W = (bb < 64) ? W1 : W2;
        unsigned short* WT = (bb < 64) ? WT1 : WT2;
        int idx = (bb & 63) * 256 + threadIdx.x;
        int k = idx >> 7, nn = idx & 127;
        WT[nn * 128 + k] = f2bf(W[idx]);
        return;
    }
    int i = b * 256 + threadIdx.x;
    if (i >= total4) return;
    int row = i >> 5;                 // 32 float4 per row
    int d = rd16(pcnt_out, row);
    float s = 1.0f / (float)(d > 1 ? d : 1);
    if ((i & 31) == 0) inv[row] = s;
    float4 v = ((const float4*)x)[i];
    uint2 o;
    o.x = pack2bf(v.x * s, v.y * s);
    o.y = pack2bf(v.z * s, v.w * s);
    xb2[i] = o;
}

// ---------------- fused layer: quarter-wave gather into LDS + MFMA 16x128 transform ----------------
template<bool OUTBF>
__global__ __launch_bounds__(256) void k_fused(
    const uint4* __restrict__ hb4, const unsigned int* __restrict__ pcnt_in,
    const int* __restrict__ esrc, const unsigned short* __restrict__ WT,
    const float* __restrict__ bias, const float* __restrict__ pa,
    const float* __restrict__ inv, void* __restrict__ outp, int n)
{
    __shared__ unsigned short sAgg[16 * PADR];   // 4.25 KB
    int wv = threadIdx.x >> 6;
    int lane = threadIdx.x & 63;
    int q = lane >> 4;    // edge sub-slot / k-chunk
    int f = lane & 15;    // 16-byte feature chunk
    int nb = blockIdx.x * 16;

    // ---- gather phase: 4 nodes per wave ----
    for (int i = 0; i < 4; i++) {
        int node = nb + wv * 4 + i;
        if (node >= n) break;
        int cnt = rd16(pcnt_in, node);
        if (cnt > CAP) cnt = CAP;
        const int* ep = esrc + (node << 6);

        float acc[8];
#pragma unroll
        for (int j = 0; j < 8; j++) acc[j] = 0.f;

        for (int base = 0; base < cnt; base += 8) {
            int e0 = base + q, e1 = base + 4 + q;
            if (e0 < cnt) {
                uint4 v = hb4[(size_t)ep[e0] * 16 + f];
                acc[0] += __uint_as_float(v.x << 16);  acc[1] += __uint_as_float(v.x & 0xffff0000u);
                acc[2] += __uint_as_float(v.y << 16);  acc[3] += __uint_as_float(v.y & 0xffff0000u);
                acc[4] += __uint_as_float(v.z << 16);  acc[5] += __uint_as_float(v.z & 0xffff0000u);
                acc[6] += __uint_as_float(v.w << 16);  acc[7] += __uint_as_float(v.w & 0xffff0000u);
            }
            if (e1 < cnt) {
                uint4 v = hb4[(size_t)ep[e1] * 16 + f];
                acc[0] += __uint_as_float(v.x << 16);  acc[1] += __uint_as_float(v.x & 0xffff0000u);
                acc[2] += __uint_as_float(v.y << 16);  acc[3] += __uint_as_float(v.y & 0xffff0000u);
                acc[4] += __uint_as_float(v.z << 16);  acc[5] += __uint_as_float(v.z & 0xffff0000u);
                acc[6] += __uint_as_float(v.w << 16);  acc[7] += __uint_as_float(v.w & 0xffff0000u);
            }
        }
#pragma unroll
        for (int j = 0; j < 8; j++) {
            acc[j] += __shfl_xor(acc[j], 16, 64);
            acc[j] += __shfl_xor(acc[j], 32, 64);
        }
        if (q == 0) {
            uint4 o;
            o.x = pack2bf(acc[0], acc[1]);
            o.y = pack2bf(acc[2], acc[3]);
            o.z = pack2bf(acc[4], acc[5]);
            o.w = pack2bf(acc[6], acc[7]);
            *(uint4*)&sAgg[(wv * 4 + i) * PADR + f * 8] = o;
        }
    }
    __syncthreads();

    // ---- transform phase: wave w does col-tiles {2w, 2w+1} ----
    int m = lane & 15;
    short8 a0 = *(const short8*)&sAgg[m * PADR +   0 + q * 8];
    short8 a1 = *(const short8*)&sAgg[m * PADR +  32 + q * 8];
    short8 a2 = *(const short8*)&sAgg[m * PADR +  64 + q * 8];
    short8 a3 = *(const short8*)&sAgg[m * PADR +  96 + q * 8];

    float alpha = pa[0];
    float* outf = (float*)outp;
    unsigned short* outb = (unsigned short*)outp;

    float invr[4];
    if (OUTBF) {
#pragma unroll
        for (int r = 0; r < 4; r++) {
            int row = nb + q * 4 + r;
            invr[r] = (row < n) ? inv[row] : 1.f;
        }
    }

#pragma unroll
    for (int tt = 0; tt < 2; tt++) {
        int t = wv * 2 + tt;
        int col = t * 16 + m;
        const short8* Bp = (const short8*)(WT + (size_t)col * 128 + q * 8);
        floatx4 acc = {0.f, 0.f, 0.f, 0.f};
        acc = __builtin_amdgcn_mfma_f32_16x16x32_bf16(a0, Bp[0],  acc, 0, 0, 0);
        acc = __builtin_amdgcn_mfma_f32_16x16x32_bf16(a1, Bp[4],  acc, 0, 0, 0);
        acc = __builtin_amdgcn_mfma_f32_16x16x32_bf16(a2, Bp[8],  acc, 0, 0, 0);
        acc = __builtin_amdgcn_mfma_f32_16x16x32_bf16(a3, Bp[12], acc, 0, 0, 0);
        float bb = bias[col];
#pragma unroll
        for (int r = 0; r < 4; r++) {
            int row = nb + q * 4 + r;   // C/D: col=lane&15, row=(lane>>4)*4+reg
            if (row < n) {
                float z = acc[r] + bb;
                z = (z >= 0.f) ? z : alpha * z;
                if (OUTBF)
                    outb[(size_t)row * 128 + col] = f2bf(z * invr[r]);
                else
                    outf[(size_t)row * 128 + col] = z;
            }
        }
    }
}

// ---------------- standalone gather (fallback path, layer 2) ----------------
__global__ __launch_bounds__(256) void k_gather(
    const uint4* __restrict__ hb4, const unsigned int* __restrict__ pcnt_in,
    const int* __restrict__ esrc, uint4* __restrict__ aggb4, int n)
{
    int lane = threadIdx.x & 63;
    int node = blockIdx.x * 4 + (threadIdx.x >> 6);
    if (node >= n) return;
    int q = lane >> 4, f = lane & 15;
    int cnt = rd16(pcnt_in, node);
    if (cnt > CAP) cnt = CAP;
    const int* ep = esrc + (node << 6);

    float acc[8];
#pragma unroll
    for (int j = 0; j < 8; j++) acc[j] = 0.f;

    for (int base = 0; base < cnt; base += 8) {
        int e0 = base + q, e1 = base + 4 + q;
        if (e0 < cnt) {
            uint4 v = hb4[(size_t)ep[e0] * 16 + f];
            acc[0] += __uint_as_float(v.x << 16);  acc[1] += __uint_as_float(v.x & 0xffff0000u);
            acc[2] += __uint_as_float(v.y << 16);  acc[3] += __uint_as_float(v.y & 0xffff0000u);
            acc[4] += __uint_as_float(v.z << 16);  acc[5] += __uint_as_float(v.z & 0xffff0000u);
            acc[6] += __uint_as_float(v.w << 16);  acc[7] += __uint_as_float(v.w & 0xffff0000u);
        }
        if (e1 < cnt) {
            uint4 v = hb4[(size_t)ep[e1] * 16 + f];
            acc[0] += __uint_as_float(v.x << 16);  acc[1] += __uint_as_float(v.x & 0xffff0000u);
            acc[2] += __uint_as_float(v.y << 16);  acc[3] += __uint_as_float(v.y & 0xffff0000u);
            acc[4] += __uint_as_float(v.z << 16);  acc[5] += __uint_as_float(v.z & 0xffff0000u);
            acc[6] += __uint_as_float(v.w << 16);  acc[7] += __uint_as_float(v.w & 0xffff0000u);
        }
    }
#pragma unroll
    for (int j = 0; j < 8; j++) {
        acc[j] += __shfl_xor(acc[j], 16, 64);
        acc[j] += __shfl_xor(acc[j], 32, 64);
    }
    if (q == 0) {
        uint4 o;
        o.x = pack2bf(acc[0], acc[1]);
        o.y = pack2bf(acc[2], acc[3]);
        o.z = pack2bf(acc[4], acc[5]);
        o.w = pack2bf(acc[6], acc[7]);
        aggb4[(size_t)node * 16 + f] = o;
    }
}

// ---------------- standalone MFMA GEMM (fallback path, layer 2) ----------------
__global__ __launch_bounds__(256) void k_gemm(
    const unsigned short* __restrict__ A, const unsigned short* __restrict__ WT,
    const float* __restrict__ bias, const float* __restrict__ pa,
    float* __restrict__ outf, int n)
{
    int lane = threadIdx.x & 63;
    int wv = threadIdx.x >> 6;
    int m = lane & 15, q = lane >> 4;
    int mbase = blockIdx.x * 64 + wv * 16;
    int arow = mbase + m;
    if (arow > n - 1) arow = n - 1;

    const short8* Ap = (const short8*)(A + (size_t)arow * 128 + q * 8);
    short8 a0 = Ap[0], a1 = Ap[4], a2 = Ap[8], a3 = Ap[12];

    float alpha = pa[0];
#pragma unroll
    for (int t = 0; t < 8; t++) {
        int col = t * 16 + m;
        const short8* Bp = (const short8*)(WT + (size_t)col * 128 + q * 8);
        floatx4 acc = {0.f, 0.f, 0.f, 0.f};
        acc = __builtin_amdgcn_mfma_f32_16x16x32_bf16(a0, Bp[0],  acc, 0, 0, 0);
        acc = __builtin_amdgcn_mfma_f32_16x16x32_bf16(a1, Bp[4],  acc, 0, 0, 0);
        acc = __builtin_amdgcn_mfma_f32_16x16x32_bf16(a2, Bp[8],  acc, 0, 0, 0);
        acc = __builtin_amdgcn_mfma_f32_16x16x32_bf16(a3, Bp[12], acc, 0, 0, 0);
        float bb = bias[col];
#pragma unroll
        for (int r = 0; r < 4; r++) {
            int row = mbase + q * 4 + r;
            if (row < n) {
                float z = acc[r] + bb;
                z = (z >= 0.f) ? z : alpha * z;
                outf[(size_t)row * 128 + col] = z;
            }
        }
    }
}

extern "C" void kernel_launch(void* const* d_in, const int* in_sizes, int n_in,
                              void* d_out, int out_size, void* d_ws, size_t ws_size,
                              hipStream_t stream) {
    const float* x   = (const float*)d_in[0];
    const int* src   = (const int*)d_in[1];
    const int* dst   = (const int*)d_in[2];
    const float* W1  = (const float*)d_in[3];
    const float* b1  = (const float*)d_in[4];
    const float* W2  = (const float*)d_in[5];
    const float* b2  = (const float*)d_in[6];
    const float* pa  = (const float*)d_in[7];
    float* out = (float*)d_out;

    const int N = in_sizes[0] / D;   // 100000
    const int E = in_sizes[1];       // 1600000

    // ---- workspace layout ----
    char* ws = (char*)d_ws;
    size_t off = 0;
    unsigned short* buf0 = (unsigned short*)(ws + off); off += (size_t)N * D * 2;  // xb; reused after layer 1
    unsigned short* buf1 = (unsigned short*)(ws + off); off += (size_t)N * D * 2;  // h1b
    unsigned int* pcnt_out = (unsigned int*)(ws + off); off += (size_t)((N + 1) / 2) * 4;
    unsigned int* pcnt_in  = (unsigned int*)(ws + off); off += (size_t)((N + 1) / 2) * 4;
    float* inv   = (float*)(ws + off); off += (size_t)N * sizeof(float);
    unsigned short* WT1 = (unsigned short*)(ws + off); off += 128 * 128 * 2;
    unsigned short* WT2 = (unsigned short*)(ws + off); off += 128 * 128 * 2;
    size_t off_esrc = off;
    size_t need_big = off_esrc + (size_t)N * CAP * sizeof(int);   // esrc in ws (~78 MB total)
    bool big = (ws_size >= need_big);

    // big path: esrc in ws -> both layers fully fused.
    // small path: esrc lives in d_out (dead before final k_gemm rewrites d_out); layer 2 split.
    int* esrc = big ? (int*)(ws + off_esrc) : (int*)d_out;

    // counting-sort structures alias onto buf1 (dead until k_fused layer 1 writes it):
    // bdata (E*4B = 6.4MB) + gcnt (NCH*nbuck*4B ~ 800KB) + btot + bstart << 25.6MB
    const int nbuck = (N + (1 << BSHIFT) - 1) >> BSHIFT;   // 782
    unsigned int* bdata  = (unsigned int*)buf1;
    unsigned int* gcnt   = bdata + E;
    unsigned int* btot   = gcnt + (size_t)NCH * nbuck;
    unsigned int* bstart = btot + nbuck;

    // zero out-degree counters (200 KB); everything else is written wholesale
    hipMemsetAsync(pcnt_out, 0, (size_t)((N + 1) / 2) * 4, stream);

    const int cs = (E + NCH - 1) / NCH;   // 6250 edges per chunk
    k_cnt <<<NCH, 512, 0, stream>>>(dst, gcnt, E, cs, nbuck);
    k_pfx1<<<nbuck, NCH, 0, stream>>>(gcnt, btot, nbuck);
    k_pfx2<<<1, 1024, 0, stream>>>(btot, bstart, nbuck, E);
    k_scat<<<NCH, 512, 0, stream>>>(src, dst, gcnt, bstart, pcnt_out, bdata, E, cs, nbuck);
    k_csr <<<nbuck, 256, 0, stream>>>(bdata, bstart, pcnt_in, esrc, N);

    const int total4 = N * (D / 4);
    const int NBP = (total4 + 255) / 256 + 128;   // prescale blocks + 128 wprep blocks
    k_prep<<<NBP, 256, 0, stream>>>(x, pcnt_out, inv, (uint2*)buf0, total4, W1, W2, WT1, WT2);

    const int NBF = (N + 15) / 16;   // fused: 16 nodes per 256-thr block

    // layer 1: buf1 = bf16(prelu(segsum(xb)@W1 + b1) * inv[row])
    k_fused<true><<<NBF, 256, 0, stream>>>((const uint4*)buf0, pcnt_in, esrc, WT1, b1, pa, inv,
                                           (void*)buf1, N);

    if (big) {
        // layer 2 fused: out = fp32 prelu(segsum(buf1)@W2 + b2)
        k_fused<false><<<NBF, 256, 0, stream>>>((const uint4*)buf1, pcnt_in, esrc, WT2, b2, pa, inv,
                                                (void*)out, N);
    } else {
        // layer 2 split: gather (esrc in d_out, dead after) then gemm writes d_out
        const int NBG = (N + 3) / 4;
        const int NBM = (N + 63) / 64;
        k_gather<<<NBG, 256, 0, stream>>>((const uint4*)buf1, pcnt_in, esrc, (uint4*)buf0, N);
        k_gemm<<<NBM, 256, 0, stream>>>(buf0, WT2, b2, pa, out, N);
    }
}

// Round 3
// 379.707 us; speedup vs baseline: 1.9481x; 1.0434x over previous
//
#include <hip/hip_runtime.h>

#define D 128
#define CAP 64    // padded CSR slots per node; P(indeg>=64 | Poisson(16)) ~ 1e-21, guarded
#define PADR 136  // shorts per LDS agg row (272 B) — breaks power-of-2 bank stride

// counting sort: bucket = dst>>7 (128 nodes/bucket), 256 deterministic chunks
#define BSHIFT 7
#define NCH 256

typedef short short8 __attribute__((ext_vector_type(8)));
typedef float floatx4 __attribute__((ext_vector_type(4)));

static __device__ __forceinline__ unsigned short f2bf(float f) {
    unsigned int u = __float_as_uint(f);
    u += 0x7fffu + ((u >> 16) & 1u);   // RNE
    return (unsigned short)(u >> 16);
}
static __device__ __forceinline__ unsigned int pack2bf(float a, float b) {
    return (unsigned int)f2bf(a) | ((unsigned int)f2bf(b) << 16);
}
// read 16-bit counter v from packed array
static __device__ __forceinline__ int rd16(const unsigned int* __restrict__ pc, int v) {
    return (int)((pc[v >> 1] >> ((v & 1) * 16)) & 0xffffu);
}
static __device__ __forceinline__ void acc8(float* a, uint4 v) {
    a[0] += __uint_as_float(v.x << 16);  a[1] += __uint_as_float(v.x & 0xffff0000u);
    a[2] += __uint_as_float(v.y << 16);  a[3] += __uint_as_float(v.y & 0xffff0000u);
    a[4] += __uint_as_float(v.z << 16);  a[5] += __uint_as_float(v.z & 0xffff0000u);
    a[6] += __uint_as_float(v.w << 16);  a[7] += __uint_as_float(v.w & 0xffff0000u);
}

// ---------------- pass 1: per-chunk bucket histogram (LDS only, no global atomics) ----------------
__global__ __launch_bounds__(512) void k_cnt(const int* __restrict__ dst,
                                             unsigned int* __restrict__ gcnt,
                                             int E, int cs, int nbuck) {
    __shared__ unsigned int h[1024];
    int b = blockIdx.x, t = threadIdx.x;
    for (int k = t; k < nbuck; k += 512) h[k] = 0;
    __syncthreads();
    int lo = b * cs, hi = lo + cs;
    if (hi > E) hi = E;
#pragma unroll 4
    for (int e = lo + t; e < hi; e += 512)
        atomicAdd(&h[(unsigned)dst[e] >> BSHIFT], 1u);
    __syncthreads();
    for (int k = t; k < nbuck; k += 512) gcnt[(size_t)b * nbuck + k] = h[k];
}

// ---------------- pass 2a: per-bucket exclusive scan over chunks (in-place) ----------------
__global__ __launch_bounds__(NCH) void k_pfx1(unsigned int* __restrict__ gcnt,
                                              unsigned int* __restrict__ btot, int nbuck) {
    __shared__ unsigned int sa[NCH], sb[NCH];
    int k = blockIdx.x, t = threadIdx.x;
    unsigned int v = gcnt[(size_t)t * nbuck + k];
    sa[t] = v;
    unsigned int* A = sa; unsigned int* B = sb;
    for (int off = 1; off < NCH; off <<= 1) {
        __syncthreads();
        B[t] = A[t] + ((t >= off) ? A[t - off] : 0u);
        unsigned int* tmp = A; A = B; B = tmp;
    }
    __syncthreads();
    unsigned int incl = A[t];
    gcnt[(size_t)t * nbuck + k] = incl - v;   // exclusive, in-place (column-private per block)
    if (t == NCH - 1) btot[k] = incl;
}

// ---------------- pass 2b: scan bucket totals -> bstart ----------------
__global__ __launch_bounds__(1024) void k_pfx2(const unsigned int* __restrict__ btot,
                                               unsigned int* __restrict__ bstart,
                                               int nbuck, int E) {
    __shared__ unsigned int sa[1024], sb[1024];
    int t = threadIdx.x;
    unsigned int v = (t < nbuck) ? btot[t] : 0u;
    sa[t] = v;
    unsigned int* A = sa; unsigned int* B = sb;
    for (int off = 1; off < 1024; off <<= 1) {
        __syncthreads();
        B[t] = A[t] + ((t >= off) ? A[t - off] : 0u);
        unsigned int* tmp = A; A = B; B = tmp;
    }
    __syncthreads();
    if (t < nbuck) bstart[t] = A[t] - v;
    if (t == 0) bstart[nbuck] = (unsigned int)E;
}

// ---------------- pass 3: deterministic scatter into dense bdata + src histogram ----------------
// Each (chunk,bucket) range is block-private and contiguous -> lines filled by one XCD.
__global__ __launch_bounds__(512) void k_scat(const int* __restrict__ src, const int* __restrict__ dst,
                                              const unsigned int* __restrict__ goff,
                                              const unsigned int* __restrict__ bstart,
                                              unsigned int* __restrict__ pcnt_out,
                                              unsigned int* __restrict__ bdata,
                                              int E, int cs, int nbuck) {
    __shared__ unsigned int cur[1024];
    int b = blockIdx.x, t = threadIdx.x;
    for (int k = t; k < nbuck; k += 512)
        cur[k] = bstart[k] + goff[(size_t)b * nbuck + k];
    __syncthreads();
    int lo = b * cs, hi = lo + cs;
    if (hi > E) hi = E;
#pragma unroll 2
    for (int e = lo + t; e < hi; e += 512) {
        int s = src[e];
        int d = dst[e];
        atomicAdd(&pcnt_out[s >> 1], 1u << ((s & 1) * 16));   // non-returning
        unsigned int p = atomicAdd(&cur[(unsigned)d >> BSHIFT], 1u);
        bdata[p] = ((unsigned int)(d & 127) << 17) | (unsigned int)s;
    }
}

// ---------------- pass 4: per-bucket CSR build (LDS counters, local scatter) ----------------
// Pads each node's slot list to a multiple of 8 with sentinel row `n` (zeroed
// feature row) so the gather inner loop needs no per-load bounds checks.
__global__ __launch_bounds__(256) void k_csr(
    const unsigned int* __restrict__ bdata, const unsigned int* __restrict__ bstart,
    unsigned int* __restrict__ pcnt_in, int* __restrict__ esrc, int n) {
    __shared__ unsigned int lcnt[128];
    int b = blockIdx.x;
    int base = b << BSHIFT;
    if (threadIdx.x < 128) lcnt[threadIdx.x] = 0;
    __syncthreads();
    int lo = (int)bstart[b], hi = (int)bstart[b + 1];
    for (int i = lo + threadIdx.x; i < hi; i += 256) {
        unsigned int e = bdata[i];
        int s = (int)(e & 0x1FFFFu);
        int dl = (int)(e >> 17);
        unsigned int p = atomicAdd(&lcnt[dl], 1u);
        if (p < CAP) esrc[((size_t)(base + dl) << 6) + p] = s;
    }
    __syncthreads();
    // sentinel padding to next multiple of 8 (<= CAP)
    if (threadIdx.x < 128) {
        int node = base + threadIdx.x;
        if (node < n) {
            int c = (int)lcnt[threadIdx.x];
            if (c > CAP) c = CAP;
            int cp = (c + 7) & ~7;
            for (int p = c; p < cp; p++)
                esrc[((size_t)node << 6) + p] = n;   // sentinel = row N (zeroed)
        }
    }
    // write packed in-degree counters wholesale (no global memset needed)
    if (threadIdx.x < 64) {
        int node0 = base + threadIdx.x * 2;
        if (node0 < n) {
            unsigned int c0 = lcnt[threadIdx.x * 2];
            unsigned int c1 = lcnt[threadIdx.x * 2 + 1];
            pcnt_in[(base >> 1) + threadIdx.x] = (c0 & 0xffffu) | (c1 << 16);
        }
    }
}

// ---------------- prep: prescale x (fused inv) + W transpose/bf16 + sentinel zero ----------------
__global__ void k_prep(const float* __restrict__ x, const unsigned int* __restrict__ pcnt_out,
                       float* __restrict__ inv, uint2* __restrict__ xb2, int total4,
                       const float* __restrict__ W1, const float* __restrict__ W2,
                       unsigned short* __restrict__ WT1, unsigned short* __restrict__ WT2,
                       uint4* __restrict__ z0, uint4* __restrict__ z1) {
    int b = blockIdx.x;
    int nb4 = (total4 + 255) >> 8;
    if (b >= nb4 + 128) {   // sentinel block: zero row N of both feature tables
        if (threadIdx.x < 16) z0[threadIdx.x] = (uint4){0u, 0u, 0u, 0u};
        else if (threadIdx.x < 32) z1[threadIdx.x - 16] = (uint4){0u, 0u, 0u, 0u};
        return;
    }
    if (b >= nb4) {  // W-prep tail blocks: 128 blocks, WT[n][k] = bf16(W[k][n])
        int bb = b - nb4;
        const float* W = (bb < 64) ? W1 : W2;
        unsigned short* WT = (bb < 64) ? WT1 : WT2;
        int idx = (bb & 63) * 256 + threadIdx.x;
        int k = idx >> 7, nn = idx & 127;
        WT[nn * 128 + k] = f2bf(W[idx]);
        return;
    }
    int i = b * 256 + threadIdx.x;
    if (i >= total4) return;
    int row = i >> 5;                 // 32 float4 per row
    int d = rd16(pcnt_out, row);
    float s = 1.0f / (float)(d > 1 ? d : 1);
    if ((i & 31) == 0) inv[row] = s;
    float4 v = ((const float4*)x)[i];
    uint2 o;
    o.x = pack2bf(v.x * s, v.y * s);
    o.y = pack2bf(v.z * s, v.w * s);
    xb2[i] = o;
}

// ---------------- fused layer: dual-node pipelined gather + MFMA 16x128 transform ----------------
template<bool OUTBF>
__global__ __launch_bounds__(256) void k_fused(
    const uint4* __restrict__ hb4, const unsigned int* __restrict__ pcnt_in,
    const int* __restrict__ esrc, const unsigned short* __restrict__ WT,
    const float* __restrict__ bias, const float* __restrict__ pa,
    const float* __restrict__ inv, void* __restrict__ outp, int n)
{
    __shared__ unsigned short sAgg[16 * PADR];   // 4.25 KB
    int wv = threadIdx.x >> 6;
    int lane = threadIdx.x & 63;
    int q = lane >> 4;    // edge sub-slot / k-chunk
    int f = lane & 15;    // 16-byte feature chunk
    int nb = blockIdx.x * 16;

    // ---- gather phase: 4 nodes per wave, processed as 2 interleaved pairs ----
    for (int ii = 0; ii < 4; ii += 2) {
        int nodeA = nb + wv * 4 + ii;
        int nodeB = nodeA + 1;
        int cA = (nodeA < n) ? rd16(pcnt_in, nodeA) : 0;
        int cB = (nodeB < n) ? rd16(pcnt_in, nodeB) : 0;
        if (cA > CAP) cA = CAP;
        if (cB > CAP) cB = CAP;
        cA = (cA + 7) & ~7;   // slots padded with sentinel in k_csr
        cB = (cB + 7) & ~7;
        const int* epA = esrc + ((size_t)nodeA << 6);
        const int* epB = esrc + ((size_t)nodeB << 6);
        float accA[8], accB[8];
#pragma unroll
        for (int j = 0; j < 8; j++) { accA[j] = 0.f; accB[j] = 0.f; }
        int mx = cA > cB ? cA : cB;
        for (int base = 0; base < mx; base += 8) {
            bool dA = base < cA, dB = base < cB;   // wave-uniform
            int2 eA, eB;
            uint4 vA0, vA1, vB0, vB1;
            if (dA) eA = *(const int2*)(epA + base + 2 * q);
            if (dB) eB = *(const int2*)(epB + base + 2 * q);
            if (dA) { vA0 = hb4[(size_t)eA.x * 16 + f]; vA1 = hb4[(size_t)eA.y * 16 + f]; }
            if (dB) { vB0 = hb4[(size_t)eB.x * 16 + f]; vB1 = hb4[(size_t)eB.y * 16 + f]; }
            if (dA) { acc8(accA, vA0); acc8(accA, vA1); }
            if (dB) { acc8(accB, vB0); acc8(accB, vB1); }
        }
#pragma unroll
        for (int j = 0; j < 8; j++) {
            accA[j] += __shfl_xor(accA[j], 16, 64);
            accA[j] += __shfl_xor(accA[j], 32, 64);
            accB[j] += __shfl_xor(accB[j], 16, 64);
            accB[j] += __shfl_xor(accB[j], 32, 64);
        }
        if (q == 0) {
            uint4 oA, oB;
            oA.x = pack2bf(accA[0], accA[1]); oA.y = pack2bf(accA[2], accA[3]);
            oA.z = pack2bf(accA[4], accA[5]); oA.w = pack2bf(accA[6], accA[7]);
            oB.x = pack2bf(accB[0], accB[1]); oB.y = pack2bf(accB[2], accB[3]);
            oB.z = pack2bf(accB[4], accB[5]); oB.w = pack2bf(accB[6], accB[7]);
            if (nodeA < n) *(uint4*)&sAgg[(wv * 4 + ii) * PADR + f * 8] = oA;
            if (nodeB < n) *(uint4*)&sAgg[(wv * 4 + ii + 1) * PADR + f * 8] = oB;
        }
    }
    __syncthreads();

    // ---- transform phase: wave w does col-tiles {2w, 2w+1} ----
    int m = lane & 15;
    short8 a0 = *(const short8*)&sAgg[m * PADR +   0 + q * 8];
    short8 a1 = *(const short8*)&sAgg[m * PADR +  32 + q * 8];
    short8 a2 = *(const short8*)&sAgg[m * PADR +  64 + q * 8];
    short8 a3 = *(const short8*)&sAgg[m * PADR +  96 + q * 8];

    float alpha = pa[0];
    float* outf = (float*)outp;
    unsigned short* outb = (unsigned short*)outp;

    float invr[4];
    if (OUTBF) {
#pragma unroll
        for (int r = 0; r < 4; r++) {
            int row = nb + q * 4 + r;
            invr[r] = (row < n) ? inv[row] : 1.f;
        }
    }

#pragma unroll
    for (int tt = 0; tt < 2; tt++) {
        int t = wv * 2 + tt;
        int col = t * 16 + m;
        const short8* Bp = (const short8*)(WT + (size_t)col * 128 + q * 8);
        floatx4 acc = {0.f, 0.f, 0.f, 0.f};
        acc = __builtin_amdgcn_mfma_f32_16x16x32_bf16(a0, Bp[0],  acc, 0, 0, 0);
        acc = __builtin_amdgcn_mfma_f32_16x16x32_bf16(a1, Bp[4],  acc, 0, 0, 0);
        acc = __builtin_amdgcn_mfma_f32_16x16x32_bf16(a2, Bp[8],  acc, 0, 0, 0);
        acc = __builtin_amdgcn_mfma_f32_16x16x32_bf16(a3, Bp[12], acc, 0, 0, 0);
        float bb = bias[col];
#pragma unroll
        for (int r = 0; r < 4; r++) {
            int row = nb + q * 4 + r;   // C/D: col=lane&15, row=(lane>>4)*4+reg
            if (row < n) {
                float z = acc[r] + bb;
                z = (z >= 0.f) ? z : alpha * z;
                if (OUTBF)
                    outb[(size_t)row * 128 + col] = f2bf(z * invr[r]);
                else
                    __builtin_nontemporal_store(z, &outf[(size_t)row * 128 + col]);
            }
        }
    }
}

// ---------------- standalone gather (fallback path, layer 2) ----------------
__global__ __launch_bounds__(256) void k_gather(
    const uint4* __restrict__ hb4, const unsigned int* __restrict__ pcnt_in,
    const int* __restrict__ esrc, uint4* __restrict__ aggb4, int n)
{
    int lane = threadIdx.x & 63;
    int node = blockIdx.x * 4 + (threadIdx.x >> 6);
    if (node >= n) return;
    int q = lane >> 4, f = lane & 15;
    int cnt = rd16(pcnt_in, node);
    if (cnt > CAP) cnt = CAP;
    cnt = (cnt + 7) & ~7;   // padded with sentinel
    const int* ep = esrc + ((size_t)node << 6);

    float acc[8];
#pragma unroll
    for (int j = 0; j < 8; j++) acc[j] = 0.f;

    for (int base = 0; base < cnt; base += 8) {
        int2 e = *(const int2*)(ep + base + 2 * q);
        uint4 v0 = hb4[(size_t)e.x * 16 + f];
        uint4 v1 = hb4[(size_t)e.y * 16 + f];
        acc8(acc, v0);
        acc8(acc, v1);
    }
#pragma unroll
    for (int j = 0; j < 8; j++) {
        acc[j] += __shfl_xor(acc[j], 16, 64);
        acc[j] += __shfl_xor(acc[j], 32, 64);
    }
    if (q == 0) {
        uint4 o;
        o.x = pack2bf(acc[0], acc[1]);
        o.y = pack2bf(acc[2], acc[3]);
        o.z = pack2bf(acc[4], acc[5]);
        o.w = pack2bf(acc[6], acc[7]);
        aggb4[(size_t)node * 16 + f] = o;
    }
}

// ---------------- standalone MFMA GEMM (fallback path, layer 2) ----------------
__global__ __launch_bounds__(256) void k_gemm(
    const unsigned short* __restrict__ A, const unsigned short* __restrict__ WT,
    const float* __restrict__ bias, const float* __restrict__ pa,
    float* __restrict__ outf, int n)
{
    int lane = threadIdx.x & 63;
    int wv = threadIdx.x >> 6;
    int m = lane & 15, q = lane >> 4;
    int mbase = blockIdx.x * 64 + wv * 16;
    int arow = mbase + m;
    if (arow > n - 1) arow = n - 1;

    const short8* Ap = (const short8*)(A + (size_t)arow * 128 + q * 8);
    short8 a0 = Ap[0], a1 = Ap[4], a2 = Ap[8], a3 = Ap[12];

    float alpha = pa[0];
#pragma unroll
    for (int t = 0; t < 8; t++) {
        int col = t * 16 + m;
        const short8* Bp = (const short8*)(WT + (size_t)col * 128 + q * 8);
        floatx4 acc = {0.f, 0.f, 0.f, 0.f};
        acc = __builtin_amdgcn_mfma_f32_16x16x32_bf16(a0, Bp[0],  acc, 0, 0, 0);
        acc = __builtin_amdgcn_mfma_f32_16x16x32_bf16(a1, Bp[4],  acc, 0, 0, 0);
        acc = __builtin_amdgcn_mfma_f32_16x16x32_bf16(a2, Bp[8],  acc, 0, 0, 0);
        acc = __builtin_amdgcn_mfma_f32_16x16x32_bf16(a3, Bp[12], acc, 0, 0, 0);
        float bb = bias[col];
#pragma unroll
        for (int r = 0; r < 4; r++) {
            int row = mbase + q * 4 + r;
            if (row < n) {
                float z = acc[r] + bb;
                z = (z >= 0.f) ? z : alpha * z;
                outf[(size_t)row * 128 + col] = z;
            }
        }
    }
}

extern "C" void kernel_launch(void* const* d_in, const int* in_sizes, int n_in,
                              void* d_out, int out_size, void* d_ws, size_t ws_size,
                              hipStream_t stream) {
    const float* x   = (const float*)d_in[0];
    const int* src   = (const int*)d_in[1];
    const int* dst   = (const int*)d_in[2];
    const float* W1  = (const float*)d_in[3];
    const float* b1  = (const float*)d_in[4];
    const float* W2  = (const float*)d_in[5];
    const float* b2  = (const float*)d_in[6];
    const float* pa  = (const float*)d_in[7];
    float* out = (float*)d_out;

    const int N = in_sizes[0] / D;   // 100000
    const int E = in_sizes[1];       // 1600000

    // ---- workspace layout (feature buffers have N+1 rows; row N = sentinel zero) ----
    char* ws = (char*)d_ws;
    size_t off = 0;
    unsigned short* buf0 = (unsigned short*)(ws + off); off += (size_t)(N + 1) * D * 2;  // xb; reused after layer 1
    unsigned short* buf1 = (unsigned short*)(ws + off); off += (size_t)(N + 1) * D * 2;  // h1b
    unsigned int* pcnt_out = (unsigned int*)(ws + off); off += (size_t)((N + 1) / 2) * 4;
    unsigned int* pcnt_in  = (unsigned int*)(ws + off); off += (size_t)((N + 1) / 2) * 4;
    float* inv   = (float*)(ws + off); off += (size_t)N * sizeof(float);
    unsigned short* WT1 = (unsigned short*)(ws + off); off += 128 * 128 * 2;
    unsigned short* WT2 = (unsigned short*)(ws + off); off += 128 * 128 * 2;
    size_t off_esrc = off;
    size_t need_big = off_esrc + (size_t)N * CAP * sizeof(int);   // esrc in ws (~78 MB total)
    bool big = (ws_size >= need_big);

    // big path: esrc in ws -> both layers fully fused.
    // small path: esrc lives in d_out (dead before final k_gemm rewrites d_out); layer 2 split.
    int* esrc = big ? (int*)(ws + off_esrc) : (int*)d_out;

    // counting-sort structures alias onto buf1 (dead until k_fused layer 1 writes it):
    // bdata (E*4B = 6.4MB) + gcnt (NCH*nbuck*4B ~ 800KB) + btot + bstart ~ 7.3MB,
    // well below buf1 row N at 25.6MB (sentinel zero write doesn't collide).
    const int nbuck = (N + (1 << BSHIFT) - 1) >> BSHIFT;   // 782
    unsigned int* bdata  = (unsigned int*)buf1;
    unsigned int* gcnt   = bdata + E;
    unsigned int* btot   = gcnt + (size_t)NCH * nbuck;
    unsigned int* bstart = btot + nbuck;

    // zero out-degree counters (200 KB); everything else is written wholesale
    hipMemsetAsync(pcnt_out, 0, (size_t)((N + 1) / 2) * 4, stream);

    const int cs = (E + NCH - 1) / NCH;   // 6250 edges per chunk
    k_cnt <<<NCH, 512, 0, stream>>>(dst, gcnt, E, cs, nbuck);
    k_pfx1<<<nbuck, NCH, 0, stream>>>(gcnt, btot, nbuck);
    k_pfx2<<<1, 1024, 0, stream>>>(btot, bstart, nbuck, E);
    k_scat<<<NCH, 512, 0, stream>>>(src, dst, gcnt, bstart, pcnt_out, bdata, E, cs, nbuck);
    k_csr <<<nbuck, 256, 0, stream>>>(bdata, bstart, pcnt_in, esrc, N);

    const int total4 = N * (D / 4);
    const int NBP = (total4 + 255) / 256 + 128 + 1;   // prescale + 128 wprep + 1 sentinel block
    uint4* z0 = (uint4*)(buf0 + (size_t)N * D);
    uint4* z1 = (uint4*)(buf1 + (size_t)N * D);
    k_prep<<<NBP, 256, 0, stream>>>(x, pcnt_out, inv, (uint2*)buf0, total4, W1, W2, WT1, WT2, z0, z1);

    const int NBF = (N + 15) / 16;   // fused: 16 nodes per 256-thr block

    // layer 1: buf1 = bf16(prelu(segsum(xb)@W1 + b1) * inv[row])
    k_fused<true><<<NBF, 256, 0, stream>>>((const uint4*)buf0, pcnt_in, esrc, WT1, b1, pa, inv,
                                           (void*)buf1, N);

    if (big) {
        // layer 2 fused: out = fp32 prelu(segsum(buf1)@W2 + b2)
        k_fused<false><<<NBF, 256, 0, stream>>>((const uint4*)buf1, pcnt_in, esrc, WT2, b2, pa, inv,
                                                (void*)out, N);
    } else {
        // layer 2 split: gather (esrc in d_out, dead after) then gemm writes d_out
        const int NBG = (N + 3) / 4;
        const int NBM = (N + 63) / 64;
        k_gather<<<NBG, 256, 0, stream>>>((const uint4*)buf1, pcnt_in, esrc, (uint4*)buf0, N);
        k_gemm<<<NBM, 256, 0, stream>>>(buf0, WT2, b2, pa, out, N);
    }
}